// Round 6
// baseline (1718.932 us; speedup 1.0000x reference)
//
#include <hip/hip_runtime.h>
#include <math.h>

// 20-step attention LSTM decoder, N=128, H=512, L=256, V=64, fp32 in/out.
// Gate GEMMs on MFMA via 3-term bf16 split (fp32-accurate).
// Attention: one-time K->bf16 and V->bf16-transposed prep, then per step:
//   k_score (grid 1024 = 128n x 8 l-partials): e-weights + per-partial (m,S)
//   k_ctx   (grid 512+16 = 128n x 4 h-slices, + fc blocks): softmax-combine + ctx
// Fallback to fp32 2-partial path if ws_size too small.

#define HH 512
#define VV 64
#define NN 128
#define LL 256
#define TT 20
#define FH 2048  // 4*H
#define LKP 136  // LDS K stride in bf16 elems (128 + 8 pad)
#define CSP 36   // C LDS row stride in f32

typedef __attribute__((ext_vector_type(8))) short bf16x8;
typedef __attribute__((ext_vector_type(4))) float f32x4;

__device__ __forceinline__ float sigf(float x) { return 1.0f / (1.0f + expf(-x)); }
__device__ __forceinline__ unsigned short f2bf(float x) {
  unsigned int u = __float_as_uint(x);
  return (unsigned short)((u + 0x7FFFu + ((u >> 16) & 1u)) >> 16);
}
__device__ __forceinline__ float bf2f(short b) {
  return __uint_as_float(((unsigned int)(unsigned short)b) << 16);
}

__device__ __forceinline__ float wred_max(float x) {
#pragma unroll
  for (int o = 32; o > 0; o >>= 1) x = fmaxf(x, __shfl_xor(x, o));
  return x;
}
__device__ __forceinline__ float wred_sum(float x) {
#pragma unroll
  for (int o = 32; o > 0; o >>= 1) x += __shfl_xor(x, o);
  return x;
}

// ---------------- init / precompute ----------------

__global__ __launch_bounds__(256) void k_init(const float* __restrict__ eh,
                                              const float* __restrict__ ec,
                                              float* __restrict__ h0,
                                              float* __restrict__ h1,
                                              float* __restrict__ cfin) {
  int i = blockIdx.x * 256 + threadIdx.x;
  const int NH4 = NN * HH / 4;
  float4 v = ((const float4*)eh)[i];
  if (i < NH4) ((float4*)h0)[i] = v;
  else         ((float4*)h1)[i - NH4] = v;
  ((float4*)cfin)[i] = ((const float4*)ec)[i];
}

// G[v][jh*4+g] = b_ih0[j]+b_hh0[j] + dot(emb[v], W_ih0[j][0:512]), j = g*512+jh
__global__ __launch_bounds__(256) void k_pre(const float* __restrict__ emb,
                                             const float* __restrict__ Wih0,
                                             const float* __restrict__ bih0,
                                             const float* __restrict__ bhh0,
                                             float* __restrict__ G) {
  int v = threadIdx.x & 63, jj = threadIdx.x >> 6;
  int j = blockIdx.x * 4 + jj;
  const float4* e4 = (const float4*)(emb + (size_t)v * HH);
  const float4* w4 = (const float4*)(Wih0 + (size_t)j * (2 * HH));
  float acc = 0.f;
#pragma unroll 8
  for (int k = 0; k < HH / 4; ++k) {
    float4 a = e4[k], b = w4[k];
    acc += a.x * b.x + a.y * b.y + a.z * b.z + a.w * b.w;
  }
  G[(size_t)v * FH + ((j & 511) << 2) + (j >> 9)] = acc + bih0[j] + bhh0[j];
}

// K -> bf16, elementwise. 8 elems/thread, grid 8192 x 256.
__global__ __launch_bounds__(256) void k_prepK(const float* __restrict__ K,
                                               unsigned short* __restrict__ Kb) {
  size_t i = ((size_t)blockIdx.x * 256 + threadIdx.x) * 8;
  float4 a = *(const float4*)(K + i);
  float4 b = *(const float4*)(K + i + 4);
  bf16x8 o;
  o[0] = f2bf(a.x); o[1] = f2bf(a.y); o[2] = f2bf(a.z); o[3] = f2bf(a.w);
  o[4] = f2bf(b.x); o[5] = f2bf(b.y); o[6] = f2bf(b.z); o[7] = f2bf(b.w);
  *(bf16x8*)(Kb + i) = o;
}

// V[n][l][h] fp32 -> Vt[n][h][l] bf16 via 64x64 LDS tile. grid 4096 = n*32+lt*8+ht.
__global__ __launch_bounds__(256) void k_prepVt(const float* __restrict__ V,
                                                unsigned short* __restrict__ Vt) {
  __shared__ float tile[64 * 65];
  int bx = blockIdx.x;
  int n = bx >> 5, lt = (bx >> 3) & 3, ht = bx & 7;
  int l0 = lt * 64, h0 = ht * 64;
  int tid = threadIdx.x;
  int r = tid >> 2, c = (tid & 3) * 16;
  const float4* src = (const float4*)(V + ((size_t)n * LL + l0 + r) * HH + h0 + c);
#pragma unroll
  for (int j = 0; j < 4; ++j) {
    float4 u = src[j];
    tile[r * 65 + c + j * 4 + 0] = u.x;
    tile[r * 65 + c + j * 4 + 1] = u.y;
    tile[r * 65 + c + j * 4 + 2] = u.z;
    tile[r * 65 + c + j * 4 + 3] = u.w;
  }
  __syncthreads();
  int hrow = tid >> 2, lcol = (tid & 3) * 16;
  bf16x8 o0, o1;
#pragma unroll
  for (int j = 0; j < 8; ++j) o0[j] = f2bf(tile[(lcol + j) * 65 + hrow]);
#pragma unroll
  for (int j = 0; j < 8; ++j) o1[j] = f2bf(tile[(lcol + 8 + j) * 65 + hrow]);
  bf16x8* dst = (bf16x8*)(Vt + ((size_t)n * HH + h0 + hrow) * LL + l0 + lcol);
  dst[0] = o0;
  dst[1] = o1;
}

// ---------------- per-step attention ----------------

#define ASCALE 0.044194173824159216f  // 1/sqrt(512)

// grid 1024: bx -> n = bx>>3, lq = bx&7 (32 keys each). 8 threads per key row.
__global__ __launch_bounds__(256) void k_score(
    const unsigned short* __restrict__ Kb, const float* __restrict__ h1cur,
    float* __restrict__ sc, float* __restrict__ msb) {
  __shared__ float qs[HH];
  __shared__ float srow[32];
  int bx = blockIdx.x, tid = threadIdx.x;
  int n = bx >> 3, lq = bx & 7;
  ((float2*)qs)[tid] = ((const float2*)(h1cur + (size_t)n * HH))[tid];
  __syncthreads();
  int row = tid >> 3, p = tid & 7;
  const bf16x8* kr =
      (const bf16x8*)(Kb + ((size_t)n * LL + lq * 32 + row) * HH + p * 64);
  float a = 0.f;
#pragma unroll
  for (int i = 0; i < 8; ++i) {
    bf16x8 kv = kr[i];
    const float* q8 = qs + p * 64 + i * 8;
#pragma unroll
    for (int j = 0; j < 8; ++j) a += bf2f(kv[j]) * q8[j];
  }
  a += __shfl_xor(a, 1);
  a += __shfl_xor(a, 2);
  a += __shfl_xor(a, 4);
  if (p == 0) srow[row] = a * ASCALE;
  __syncthreads();
  if (tid < 32) {
    float x = srow[tid];
    float m = x;
#pragma unroll
    for (int o = 16; o > 0; o >>= 1) m = fmaxf(m, __shfl_xor(m, o));
    float e = expf(x - m);
    float s = e;
#pragma unroll
    for (int o = 16; o > 0; o >>= 1) s += __shfl_xor(s, o);
    sc[(size_t)n * LL + lq * 32 + tid] = e;
    if (tid == 0) {
      float2 v2 = {m, s};
      *(float2*)(msb + ((size_t)lq * NN + n) * 2) = v2;
    }
  }
}

// grid 512 (+16 fc blocks if DO_FC): bx<512 -> n = bx>>2, ht = bx&3 (128 h each,
// 2-way l split). bx>=512 -> fc/softmax for tprev over an 8-sample tile.
template <bool DO_FC>
__global__ __launch_bounds__(256) void k_ctx(
    const unsigned short* __restrict__ Vt, const float* __restrict__ sc,
    const float* __restrict__ msb, float* __restrict__ ctx,
    const float* __restrict__ h1cur, const float* __restrict__ fc_w,
    const float* __restrict__ fc_b, float* __restrict__ probs, int tprev) {
  __shared__ float att[LL];
  __shared__ float redP[128];
  __shared__ float hs[8 * HH];
  int bx = blockIdx.x, tid = threadIdx.x;

  if (DO_FC && bx >= 512) {
    int n0 = (bx - 512) * 8;
    // stage 8 h1 rows (4096 f32) -> 4 float4/thread
#pragma unroll
    for (int i = 0; i < 4; ++i) {
      int fi = tid + i * 256;  // float4 idx 0..1023
      int r = fi >> 7, k4 = fi & 127;
      ((float4*)hs)[r * 128 + k4] =
          ((const float4*)(h1cur + (size_t)(n0 + r) * HH))[k4];
    }
    __syncthreads();
    int nl = tid >> 5, vb = (tid & 31) * 2;
    const float4* h4 = (const float4*)(hs + nl * HH);
    const float4* w0 = (const float4*)(fc_w + (size_t)vb * HH);
    const float4* w1 = (const float4*)(fc_w + (size_t)(vb + 1) * HH);
    float a0 = 0.f, a1 = 0.f;
#pragma unroll 8
    for (int k = 0; k < 128; ++k) {
      float4 h = h4[k], x0 = w0[k], x1 = w1[k];
      a0 += h.x * x0.x + h.y * x0.y + h.z * x0.z + h.w * x0.w;
      a1 += h.x * x1.x + h.y * x1.y + h.z * x1.z + h.w * x1.w;
    }
    a0 += fc_b[vb];
    a1 += fc_b[vb + 1];
    float m = fmaxf(a0, a1);
#pragma unroll
    for (int o = 16; o > 0; o >>= 1) m = fmaxf(m, __shfl_xor(m, o));
    float e0 = expf(a0 - m), e1 = expf(a1 - m);
    float s = e0 + e1;
#pragma unroll
    for (int o = 16; o > 0; o >>= 1) s += __shfl_xor(s, o);
    float inv = 1.f / s;
    float2 pr = {e0 * inv, e1 * inv};
    *(float2*)(probs + ((size_t)(n0 + nl) * TT + tprev) * VV + vb) = pr;
    return;
  }

  int n = bx >> 2, ht = bx & 3;
  int hl = tid & 127, lg = tid >> 7;
  // softmax combine across 8 partials
  float mp[8], sp[8];
#pragma unroll
  for (int i = 0; i < 8; ++i) {
    float2 v2 = *(const float2*)(msb + ((size_t)i * NN + n) * 2);
    mp[i] = v2.x;
    sp[i] = v2.y;
  }
  float m = mp[0];
#pragma unroll
  for (int i = 1; i < 8; ++i) m = fmaxf(m, mp[i]);
  float S = 0.f;
#pragma unroll
  for (int i = 0; i < 8; ++i) {
    mp[i] = expf(mp[i] - m);
    S += sp[i] * mp[i];
  }
  float invS = 1.f / S;
  {
    int l = tid;  // 0..255
    att[l] = sc[(size_t)n * LL + l] * mp[l >> 5] * invS;
  }
  __syncthreads();

  int h = ht * 128 + hl;
  const bf16x8* vt =
      (const bf16x8*)(Vt + ((size_t)n * HH + h) * LL + lg * 128);
  const float* ab = att + lg * 128;
  float acc = 0.f;
#pragma unroll
  for (int i = 0; i < 16; ++i) {
    bf16x8 v8 = vt[i];
    const float* a8 = ab + i * 8;
#pragma unroll
    for (int j = 0; j < 8; ++j) acc += bf2f(v8[j]) * a8[j];
  }
  if (lg == 1) redP[hl] = acc;
  __syncthreads();
  if (lg == 0) ctx[(size_t)n * HH + h] = acc + redP[hl];
}

// fc+softmax for t=T-1 and copy final h states. grid 128 (one-time).
__global__ __launch_bounds__(256) void k_final(
    const float* __restrict__ h1cur, const float* __restrict__ h0cur,
    const float* __restrict__ fc_w, const float* __restrict__ fc_b,
    float* __restrict__ probs, float* __restrict__ hfin) {
  __shared__ float qs[HH];
  __shared__ float lg[VV];
  int n = blockIdx.x, tid = threadIdx.x;
  ((float2*)qs)[tid] = ((const float2*)(h1cur + (size_t)n * HH))[tid];
  ((float2*)(hfin + (size_t)n * HH))[tid] =
      ((const float2*)(h0cur + (size_t)n * HH))[tid];
  ((float2*)(hfin + (size_t)(NN + n) * HH))[tid] =
      ((const float2*)(h1cur + (size_t)n * HH))[tid];
  __syncthreads();
  int v = tid >> 2, p = tid & 3;
  const float4* wr = (const float4*)(fc_w + (size_t)v * HH + p * 128);
  const float4* q4 = (const float4*)(qs + p * 128);
  float a = 0.f;
#pragma unroll 8
  for (int k = 0; k < 32; ++k) {
    float4 w = wr[k], q = q4[k];
    a += w.x * q.x + w.y * q.y + w.z * q.z + w.w * q.w;
  }
  a += __shfl_xor(a, 1);
  a += __shfl_xor(a, 2);
  if (p == 0) lg[v] = a + fc_b[v];
  __syncthreads();
  if (tid < VV) {
    float x = lg[tid];
    float m = wred_max(x);
    float e = expf(x - m);
    float s = wred_sum(e);
    probs[((size_t)n * TT + TT - 1) * VV + tid] = e / s;
  }
}

// ---------------- fallback fp32 attention (round-3) ----------------

template <bool DO_FC>
__global__ __launch_bounds__(256) void k_attn2(
    const float* __restrict__ key, const float* __restrict__ value,
    const float* __restrict__ h1cur,
    const float* __restrict__ fc_w, const float* __restrict__ fc_b,
    float* __restrict__ probs, int tprev,
    float* __restrict__ ctxp, float* __restrict__ ms) {
  __shared__ float qs[HH];
  __shared__ float scp[2][128];
  __shared__ float att[128];
  __shared__ float lg[VV];
  __shared__ float red[4];
  int b = blockIdx.x, n = b >> 1, half = b & 1, tid = threadIdx.x;
  ((float2*)qs)[tid] = ((const float2*)(h1cur + (size_t)n * HH))[tid];
  __syncthreads();

  if (DO_FC && half == 0) {
    int v = tid >> 2, p = tid & 3;
    const float4* wr = (const float4*)(fc_w + (size_t)v * HH + p * 128);
    const float4* q4 = (const float4*)(qs + p * 128);
    float a = 0.f;
#pragma unroll 8
    for (int k = 0; k < 32; ++k) {
      float4 w = wr[k], q = q4[k];
      a += w.x * q.x + w.y * q.y + w.z * q.z + w.w * q.w;
    }
    a += __shfl_xor(a, 1);
    a += __shfl_xor(a, 2);
    if (p == 0) lg[v] = a + fc_b[v];
    __syncthreads();
    if (tid < VV) {
      float x = lg[tid];
      float m = wred_max(x);
      float e = expf(x - m);
      float s = wred_sum(e);
      probs[((size_t)n * TT + tprev) * VV + tid] = e / s;
    }
  }

  int ll = tid & 127, p = tid >> 7;
  {
    const float4* kr =
        (const float4*)(key + ((size_t)n * LL + half * 128 + ll) * HH + p * 256);
    const float4* q4 = (const float4*)(qs + p * 256);
    float a = 0.f;
#pragma unroll 8
    for (int k = 0; k < 64; ++k) {
      float4 w = kr[k], q = q4[k];
      a += w.x * q.x + w.y * q.y + w.z * q.z + w.w * q.w;
    }
    scp[p][ll] = a;
  }
  __syncthreads();

  float x = 0.f;
  if (tid < 128) {
    x = (scp[0][tid] + scp[1][tid]) * ASCALE;
    float m = wred_max(x);
    if ((tid & 63) == 0) red[tid >> 6] = m;
  }
  __syncthreads();
  float m_p = fmaxf(red[0], red[1]);
  if (tid < 128) {
    float e = expf(x - m_p);
    att[tid] = e;
    float s = wred_sum(e);
    if ((tid & 63) == 0) red[2 + (tid >> 6)] = s;
  }
  __syncthreads();
  if (tid == 0) {
    float2 v2 = {m_p, red[2] + red[3]};
    *(float2*)(ms + ((size_t)half * NN + n) * 2) = v2;
  }

  const float* vb = value + ((size_t)n * LL + half * 128) * HH + 2 * tid;
  float cx = 0.f, cy = 0.f;
#pragma unroll 4
  for (int l2 = 0; l2 < 128; ++l2) {
    float a2 = att[l2];
    float2 v2 = *(const float2*)(vb + (size_t)l2 * HH);
    cx += a2 * v2.x;
    cy += a2 * v2.y;
  }
  float2 o2 = {cx, cy};
  ((float2*)(ctxp + ((size_t)half * NN + n) * HH))[tid] = o2;
}

// ---------------- MFMA gate-GEMM + fused LSTM cell ----------------
// MODE: 0 = bias init (layer 1); 1 = G[tok] init, single ctx (new path);
//       2 = G[tok] init + 2-partial ctx combine (fallback path).
template <int MODE>
__global__ __launch_bounds__(256) void k_gemm(
    const float* __restrict__ Ax0, const float* __restrict__ Ax1,
    const float* __restrict__ Ahh,
    const float* __restrict__ W0, int ws0,
    const float* __restrict__ W1, int ws1,
    const int* __restrict__ word, const float* __restrict__ G,
    const float* __restrict__ bih, const float* __restrict__ bhh,
    const float* __restrict__ ms,
    float* __restrict__ cbuf, float* __restrict__ hnext, int t) {
  __shared__ __align__(16) unsigned short AhS[32 * LKP];
  __shared__ __align__(16) unsigned short AlS[32 * LKP];
  __shared__ __align__(16) unsigned short WhS[32 * LKP];
  __shared__ __align__(16) unsigned short WlS[32 * LKP];
  __shared__ float sc0s[32], sc1s[32];
  __shared__ __align__(16) float Cs[32 * CSP];

  int tid = threadIdx.x;
  int mt = blockIdx.x & 3, nt = blockIdx.x >> 2;
  int s0 = mt * 32, n0 = nt * 32;

  int r = tid >> 3, kq = tid & 7, kk = kq * 16;
  int rowp = n0 + r;
  int jrow = (rowp & 3) * 512 + (rowp >> 2);

  if (MODE == 2 && tid < 32) {
    int n = s0 + tid;
    float m0 = ms[2 * n], sa = ms[2 * n + 1];
    float m1 = ms[2 * (NN + n)], sb = ms[2 * (NN + n) + 1];
    float m = fmaxf(m0, m1);
    float e0 = expf(m0 - m), e1 = expf(m1 - m);
    float S = sa * e0 + sb * e1;
    sc0s[tid] = e0 / S;
    sc1s[tid] = e1 / S;
  }

  float4 aR0[4], aR1[4], wRg[4];

  auto LOADC = [&](int c) {
    int k0 = c * 128;
    if (k0 < 512) {
      const float4* p0 = (const float4*)(Ax0 + (size_t)(s0 + r) * HH + k0 + kk);
#pragma unroll
      for (int i = 0; i < 4; ++i) aR0[i] = p0[i];
      if (MODE == 2) {
        const float4* p1 = (const float4*)(Ax1 + (size_t)(s0 + r) * HH + k0 + kk);
#pragma unroll
        for (int i = 0; i < 4; ++i) aR1[i] = p1[i];
      }
      const float4* wp = (const float4*)(W0 + (size_t)jrow * ws0 + k0 + kk);
#pragma unroll
      for (int i = 0; i < 4; ++i) wRg[i] = wp[i];
    } else {
      const float4* p0 =
          (const float4*)(Ahh + (size_t)(s0 + r) * HH + (k0 - 512) + kk);
#pragma unroll
      for (int i = 0; i < 4; ++i) aR0[i] = p0[i];
      const float4* wp = (const float4*)(W1 + (size_t)jrow * ws1 + (k0 - 512) + kk);
#pragma unroll
      for (int i = 0; i < 4; ++i) wRg[i] = wp[i];
    }
  };

  auto STOREC = [&](int c) {
    int k0 = c * 128;
    bool cmb = (MODE == 2) && (k0 < 512);
    float sa = cmb ? sc0s[r] : 0.f, sb = cmb ? sc1s[r] : 0.f;
#pragma unroll
    for (int i = 0; i < 2; ++i) {
      float xa[8], xw[8];
      float4 u0 = aR0[2 * i], u1 = aR0[2 * i + 1];
      xa[0] = u0.x; xa[1] = u0.y; xa[2] = u0.z; xa[3] = u0.w;
      xa[4] = u1.x; xa[5] = u1.y; xa[6] = u1.z; xa[7] = u1.w;
      if (cmb) {
        float4 v0 = aR1[2 * i], v1 = aR1[2 * i + 1];
        xa[0] = sa * xa[0] + sb * v0.x; xa[1] = sa * xa[1] + sb * v0.y;
        xa[2] = sa * xa[2] + sb * v0.z; xa[3] = sa * xa[3] + sb * v0.w;
        xa[4] = sa * xa[4] + sb * v1.x; xa[5] = sa * xa[5] + sb * v1.y;
        xa[6] = sa * xa[6] + sb * v1.z; xa[7] = sa * xa[7] + sb * v1.w;
      }
      float4 w0 = wRg[2 * i], w1 = wRg[2 * i + 1];
      xw[0] = w0.x; xw[1] = w0.y; xw[2] = w0.z; xw[3] = w0.w;
      xw[4] = w1.x; xw[5] = w1.y; xw[6] = w1.z; xw[7] = w1.w;
      bf16x8 ah, al, wh, wl;
#pragma unroll
      for (int j = 0; j < 8; ++j) {
        unsigned int u = __float_as_uint(xa[j]);
        unsigned int hb = (u + 0x7FFFu + ((u >> 16) & 1u)) & 0xFFFF0000u;
        ah[j] = (short)(hb >> 16);
        float lo = xa[j] - __uint_as_float(hb);
        al[j] = (short)f2bf(lo);
        u = __float_as_uint(xw[j]);
        hb = (u + 0x7FFFu + ((u >> 16) & 1u)) & 0xFFFF0000u;
        wh[j] = (short)(hb >> 16);
        lo = xw[j] - __uint_as_float(hb);
        wl[j] = (short)f2bf(lo);
      }
      int off = r * LKP + kk + i * 8;
      *(bf16x8*)(AhS + off) = ah;
      *(bf16x8*)(AlS + off) = al;
      *(bf16x8*)(WhS + off) = wh;
      *(bf16x8*)(WlS + off) = wl;
    }
  };

  f32x4 acc0 = {0.f, 0.f, 0.f, 0.f};
  f32x4 acc1 = {0.f, 0.f, 0.f, 0.f};
  f32x4 acc2 = {0.f, 0.f, 0.f, 0.f};
  int lane = tid & 63, wv = tid >> 6;
  int wm = wv >> 1, wn = wv & 1;
  int aoff = (wm * 16 + (lane & 15)) * LKP;
  int woff = (wn * 16 + (lane & 15)) * LKP;
  int kb = (lane >> 4) * 8;

  LOADC(0);
  __syncthreads();
  for (int c = 0; c < 8; ++c) {
    if (c) __syncthreads();
    STOREC(c);
    __syncthreads();
    if (c < 7) LOADC(c + 1);
#pragma unroll
    for (int ks = 0; ks < 4; ++ks) {
      int ko = kb + ks * 32;
      bf16x8 ah = *(const bf16x8*)(AhS + aoff + ko);
      bf16x8 al = *(const bf16x8*)(AlS + aoff + ko);
      bf16x8 wh = *(const bf16x8*)(WhS + woff + ko);
      bf16x8 wl = *(const bf16x8*)(WlS + woff + ko);
      acc0 = __builtin_amdgcn_mfma_f32_16x16x32_bf16(ah, wh, acc0, 0, 0, 0);
      acc1 = __builtin_amdgcn_mfma_f32_16x16x32_bf16(al, wh, acc1, 0, 0, 0);
      acc2 = __builtin_amdgcn_mfma_f32_16x16x32_bf16(ah, wl, acc2, 0, 0, 0);
    }
  }

  __syncthreads();
  f32x4 cv = acc0 + acc1;
  cv = cv + acc2;
  int crow = wm * 16 + (lane >> 4) * 4, ccol = wn * 16 + (lane & 15);
#pragma unroll
  for (int q = 0; q < 4; ++q) Cs[(crow + q) * CSP + ccol] = cv[q];
  __syncthreads();
  int s_l = tid >> 3, jh_l = tid & 7;
  int s = s0 + s_l, jh = nt * 8 + jh_l;
  f32x4 c4 = *(const f32x4*)(Cs + s_l * CSP + jh_l * 4);
  if (MODE >= 1) {
    int tok = (t == 0) ? 0 : (word[s * TT + t - 1] & 63);
    f32x4 g4 = *(const f32x4*)(G + (size_t)tok * FH + jh * 4);
    c4 = c4 + g4;
  } else {
    c4[0] += bih[jh] + bhh[jh];
    c4[1] += bih[512 + jh] + bhh[512 + jh];
    c4[2] += bih[1024 + jh] + bhh[1024 + jh];
    c4[3] += bih[1536 + jh] + bhh[1536 + jh];
  }
  float c_old = cbuf[(size_t)s * HH + jh];
  float cn = sigf(c4[1]) * c_old + sigf(c4[0]) * tanhf(c4[2]);
  cbuf[(size_t)s * HH + jh] = cn;
  hnext[(size_t)s * HH + jh] = sigf(c4[3]) * tanhf(cn);
}

// ---------------- host ----------------

extern "C" void kernel_launch(void* const* d_in, const int* in_sizes, int n_in,
                              void* d_out, int out_size, void* d_ws, size_t ws_size,
                              hipStream_t stream) {
  const float* key   = (const float*)d_in[0];
  const float* value = (const float*)d_in[1];
  const float* eh    = (const float*)d_in[2];
  const float* ec    = (const float*)d_in[3];
  const int*   word  = (const int*)d_in[4];
  const float* emb   = (const float*)d_in[5];
  const float* Wih0  = (const float*)d_in[6];
  const float* Whh0  = (const float*)d_in[7];
  const float* bih0  = (const float*)d_in[8];
  const float* bhh0  = (const float*)d_in[9];
  const float* Wih1  = (const float*)d_in[10];
  const float* Whh1  = (const float*)d_in[11];
  const float* bih1  = (const float*)d_in[12];
  const float* bhh1  = (const float*)d_in[13];
  const float* fcw   = (const float*)d_in[14];
  const float* fcb   = (const float*)d_in[15];

  float* out   = (float*)d_out;
  float* probs = out;                         // (N, T, V)
  float* hfin  = out + (size_t)NN * TT * VV;  // (2, N, H)
  float* cfin  = hfin + 2 * (size_t)NN * HH;  // (2, N, H) -- live c state

  float* ws = (float*)d_ws;
  // new-path layout (floats)
  float* G    = ws;                            // 131072
  float* ctx  = G + 131072;                    // 65536
  float* h0a  = ctx + 65536;
  float* h0b  = h0a + 65536;
  float* h1a  = h0b + 65536;
  float* h1b  = h1a + 65536;
  float* sc   = h1b + 65536;                   // 32768
  float* msb  = sc + 32768;                    // 4096 (8*128*2 used)
  unsigned short* Kb = (unsigned short*)(msb + 4096);   // 16.8M bf16
  unsigned short* Vt = Kb + (size_t)NN * LL * HH;       // 16.8M bf16
  const size_t NEED = ((size_t)131072 + 65536 * 5 + 32768 + 4096) * 4 +
                      (size_t)2 * NN * LL * HH * 2;     // ~69.1 MB

  k_init<<<128, 256, 0, stream>>>(eh, ec, h0a, h1a, cfin);
  k_pre<<<512, 256, 0, stream>>>(emb, Wih0, bih0, bhh0, G);

  float* h0c = h0a; float* h0n = h0b;
  float* h1c = h1a; float* h1n = h1b;

  if (ws_size >= NEED) {
    k_prepK<<<8192, 256, 0, stream>>>(key, Kb);
    k_prepVt<<<4096, 256, 0, stream>>>(value, Vt);

    for (int t = 0; t < TT; ++t) {
      k_score<<<1024, 256, 0, stream>>>(Kb, h1c, sc, msb);
      if (t == 0)
        k_ctx<false><<<512, 256, 0, stream>>>(Vt, sc, msb, ctx, h1c, fcw, fcb,
                                              probs, 0);
      else
        k_ctx<true><<<528, 256, 0, stream>>>(Vt, sc, msb, ctx, h1c, fcw, fcb,
                                             probs, t - 1);
      k_gemm<1><<<256, 256, 0, stream>>>(
          ctx, (const float*)nullptr, h0c, Wih0 + 512, 2 * HH, Whh0, HH,
          word, G, bih0, bhh0, (const float*)nullptr, cfin, h0n, t);
      k_gemm<0><<<256, 256, 0, stream>>>(
          h0n, (const float*)nullptr, h1c, Wih1, HH, Whh1, HH,
          word, G, bih1, bhh1, (const float*)nullptr,
          cfin + (size_t)NN * HH, h1n, t);
      float* tmp;
      tmp = h0c; h0c = h0n; h0n = tmp;
      tmp = h1c; h1c = h1n; h1n = tmp;
    }
  } else {
    // fallback: fp32 2-partial attention (round-3 path)
    float* ctxp = G + 131072;
    float* ms2 = ctxp + 131072;
    float* f0a = ms2 + 512;
    float* f0b = f0a + 65536;
    float* f1a = f0b + 65536;
    float* f1b = f1a + 65536;
    k_init<<<128, 256, 0, stream>>>(eh, ec, f0a, f1a, cfin);
    h0c = f0a; h0n = f0b; h1c = f1a; h1n = f1b;
    for (int t = 0; t < TT; ++t) {
      if (t == 0)
        k_attn2<false><<<256, 256, 0, stream>>>(key, value, h1c, fcw, fcb,
                                                probs, 0, ctxp, ms2);
      else
        k_attn2<true><<<256, 256, 0, stream>>>(key, value, h1c, fcw, fcb,
                                               probs, t - 1, ctxp, ms2);
      k_gemm<2><<<256, 256, 0, stream>>>(
          ctxp, ctxp + (size_t)NN * HH, h0c, Wih0 + 512, 2 * HH, Whh0, HH,
          word, G, bih0, bhh0, ms2, cfin, h0n, t);
      k_gemm<0><<<256, 256, 0, stream>>>(
          h0n, (const float*)nullptr, h1c, Wih1, HH, Whh1, HH,
          word, G, bih1, bhh1, (const float*)nullptr,
          cfin + (size_t)NN * HH, h1n, t);
      float* tmp;
      tmp = h0c; h0c = h0n; h0n = tmp;
      tmp = h1c; h1c = h1n; h1n = tmp;
    }
  }

  k_final<<<128, 256, 0, stream>>>(h1c, h0c, fcw, fcb, probs, hfin);
}